// Round 8
// baseline (382.937 us; speedup 1.0000x reference)
//
#include <hip/hip_runtime.h>

#define D 64

// --- degree histogram over dst, dst-sliced for XCD-local atomics -----------
__global__ void count_deg_sliced_kernel(const int* __restrict__ dst, int* __restrict__ deg,
                                        int nE, int slice_size) {
    const int g  = blockIdx.x & 7;    // slice id == XCD id (perf heuristic)
    const int gb = blockIdx.x >> 3;
    const int lo = g * slice_size;
    const int hi = lo + slice_size;
    int e4 = (gb * 256 + (int)threadIdx.x) * 4;
    if (e4 + 3 < nE) {
        int4 d = *(const int4*)(dst + e4);
        if (d.x >= lo && d.x < hi) atomicAdd(&deg[d.x], 1);
        if (d.y >= lo && d.y < hi) atomicAdd(&deg[d.y], 1);
        if (d.z >= lo && d.z < hi) atomicAdd(&deg[d.z], 1);
        if (d.w >= lo && d.w < hi) atomicAdd(&deg[d.w], 1);
    } else if (e4 < nE) {
        for (int e = e4; e < nE; ++e) {
            int dd = dst[e];
            if (dd >= lo && dd < hi) atomicAdd(&deg[dd], 1);
        }
    }
}

// --- hierarchical exclusive scan: A (per-block tile scan) ------------------
__global__ __launch_bounds__(256) void scan_a_kernel(const int* __restrict__ deg,
                                                     int* __restrict__ row_ptr,
                                                     int* __restrict__ blocksums, int N) {
    __shared__ int s[256];
    int t = threadIdx.x;
    int i = blockIdx.x * 256 + t;
    int v = (i < N) ? deg[i] : 0;
    s[t] = v;
    __syncthreads();
    #pragma unroll
    for (int d = 1; d < 256; d <<= 1) {
        int u = (t >= d) ? s[t - d] : 0;
        __syncthreads();
        s[t] += u;
        __syncthreads();
    }
    if (i < N) row_ptr[i] = s[t] - v;             // exclusive (block-local)
    if (t == 255) blocksums[blockIdx.x] = s[255]; // block total
}

// --- B: single-block exclusive scan of block sums (nb <= 256) --------------
__global__ __launch_bounds__(256) void scan_b_kernel(int* __restrict__ blocksums,
                                                     int* __restrict__ row_ptr,
                                                     int nb, int N) {
    __shared__ int s[256];
    int t = threadIdx.x;
    int v = (t < nb) ? blocksums[t] : 0;
    s[t] = v;
    __syncthreads();
    #pragma unroll
    for (int d = 1; d < 256; d <<= 1) {
        int u = (t >= d) ? s[t - d] : 0;
        __syncthreads();
        s[t] += u;
        __syncthreads();
    }
    if (t < nb) blocksums[t] = s[t] - v;  // exclusive block offsets
    if (t == 255) row_ptr[N] = s[255];    // total = E
}

// --- C: apply block offsets, emit final row_ptr + cursor -------------------
__global__ __launch_bounds__(256) void scan_c_kernel(int* __restrict__ row_ptr,
                                                     int* __restrict__ cursor,
                                                     const int* __restrict__ blocksums, int N) {
    int i = blockIdx.x * 256 + threadIdx.x;
    if (i < N) {
        int r = row_ptr[i] + blocksums[blockIdx.x];
        row_ptr[i] = r;
        cursor[i] = r;
    }
}

// --- bucket edges by dst: col[pos] = src, dst-sliced for XCD locality ------
__global__ __launch_bounds__(256) void fill_csr_sliced_kernel(
    const int* __restrict__ src, const int* __restrict__ dst,
    int* __restrict__ cursor, int* __restrict__ col,
    int nE, int slice_size)
{
    const int g  = blockIdx.x & 7;    // slice id == XCD id (perf heuristic)
    const int gb = blockIdx.x >> 3;   // block index within group
    const int lo = g * slice_size;
    const int hi = lo + slice_size;
    int e4 = (gb * 256 + (int)threadIdx.x) * 4;
    if (e4 + 3 < nE) {
        int4 d = *(const int4*)(dst + e4);
        bool m0 = (d.x >= lo) & (d.x < hi);
        bool m1 = (d.y >= lo) & (d.y < hi);
        bool m2 = (d.z >= lo) & (d.z < hi);
        bool m3 = (d.w >= lo) & (d.w < hi);
        if (m0 | m1 | m2 | m3) {
            int4 s = *(const int4*)(src + e4);
            if (m0) col[atomicAdd(&cursor[d.x], 1)] = s.x;
            if (m1) col[atomicAdd(&cursor[d.y], 1)] = s.y;
            if (m2) col[atomicAdd(&cursor[d.z], 1)] = s.z;
            if (m3) col[atomicAdd(&cursor[d.w], 1)] = s.w;
        }
    } else if (e4 < nE) {
        for (int e = e4; e < nE; ++e) {
            int dd = dst[e];
            if (dd >= lo && dd < hi) col[atomicAdd(&cursor[dd], 1)] = src[e];
        }
    }
}

// --- phase 1: feature-sliced gather + normalize ----------------------------
// t[i] = (sum_{s in N(i)} h[s] + h[i]) / (deg+1)
// Group g = blockIdx&7 -> XCD g handles feature chunk (g&3)*16..+16 (exactly
// one 64B line) for node half g>>2. Each XCD's gather working set is
// N*64B = 3.2MB < 4MB L2 -> near-full L2 residency (was: whole 12.8MB h per
// XCD, 81MB LLC spill). Wave = 4 edge-subgroups x 16 feature lanes.
__global__ __launch_bounds__(256, 4) void sage_gather_kernel(
    const float* __restrict__ h, const int* __restrict__ row_ptr,
    const int* __restrict__ col, float* __restrict__ t, int N)
{
    const int g     = blockIdx.x & 7;
    const int chunk = g & 3;          // feature chunk 0..3
    const int half  = g >> 2;         // node half 0..1
    const int gb    = blockIdx.x >> 3;
    const int lane  = threadIdx.x & 63;
    const int sub   = lane >> 4;      // edge subgroup 0..3
    const int f     = lane & 15;      // feature within chunk
    const int fcol  = chunk * 16 + f; // absolute feature index
    const int w     = threadIdx.x >> 6;

    const int Nh = (N + 1) >> 1;
    const int lo = half * Nh;
    const int hi = (lo + Nh < N) ? (lo + Nh) : N;
    const int waves_per_group = (gridDim.x >> 3) * 4;

    for (int i0 = lo + gb * 4 + w; i0 < hi; i0 += waves_per_group) {
        const int i  = __builtin_amdgcn_readfirstlane(i0);
        const int rs = __builtin_amdgcn_readfirstlane(row_ptr[i]);
        const int re = __builtin_amdgcn_readfirstlane(row_ptr[i + 1]);
        const int deg = re - rs;

        float a0 = 0.f, a1 = 0.f, a2 = 0.f, a3 = 0.f;
        for (int e0 = rs; e0 < re; e0 += 64) {
            int ee = e0 + lane;
            int idx = col[(ee < re) ? ee : (re - 1)];
            int rem = re - e0;
            int steps = (((rem < 64) ? rem : 64) + 3) >> 2;
            int tt = 0;
            for (; tt + 4 <= steps; tt += 4) {
                int base = (tt << 2) + sub;
                int s0 = __shfl(idx, base);
                int s1 = __shfl(idx, base + 4);
                int s2 = __shfl(idx, base + 8);
                int s3 = __shfl(idx, base + 12);
                a0 += h[(size_t)s0 * D + fcol];
                a1 += h[(size_t)s1 * D + fcol];
                a2 += h[(size_t)s2 * D + fcol];
                a3 += h[(size_t)s3 * D + fcol];
            }
            for (; tt < steps; ++tt) {
                int s0 = __shfl(idx, (tt << 2) + sub);
                a0 += h[(size_t)s0 * D + fcol];
            }
        }

        float tv = (a0 + a1) + (a2 + a3);
        tv += __shfl_xor(tv, 16);
        tv += __shfl_xor(tv, 32);

        int pad = (-deg) & 3;     // clamped duplicate count of col[re-1]
        if (deg > 0 && pad) {
            int last = __builtin_amdgcn_readfirstlane(col[re - 1]);
            tv = fmaf(-(float)pad, h[(size_t)last * D + fcol], tv);
        }
        tv = (tv + h[(size_t)i * D + fcol]) * (1.0f / (float)(deg + 1));

        if (lane < 16) t[(size_t)i * D + fcol] = tv;   // one full 64B line
    }
}

// --- phase 2: dense MLP out = relu?(t @ W + b) -----------------------------
// Wave per node; W staged in LDS (Ws[k*64+lane]: 2 lanes/bank = free);
// t-row broadcast via readlane (proven R6 epilogue pattern).
__global__ __launch_bounds__(256) void sage_mlp_kernel(
    const float* __restrict__ t, const float* __restrict__ W,
    const float* __restrict__ bias, float* __restrict__ out,
    int N, int do_relu)
{
    __shared__ float Ws[D * D];
    for (int i = threadIdx.x; i < D * D; i += 256) Ws[i] = W[i];
    const int lane = threadIdx.x & 63;
    const int fq   = lane & 15;
    const int w    = threadIdx.x >> 6;
    const float bj = bias[lane];
    __syncthreads();

    const float4* __restrict__ t4 = (const float4*)t;
    const int nwaves = gridDim.x * 4;
    for (int i0 = blockIdx.x * 4 + w; i0 < N; i0 += nwaves) {
        const int i = __builtin_amdgcn_readfirstlane(i0);
        float4 tv = t4[(size_t)i * 16 + fq];   // lanes replicate row quads
        float o = bj;
        #pragma unroll
        for (int k = 0; k < D; ++k) {
            float comp = ((k & 3) == 0) ? tv.x : ((k & 3) == 1) ? tv.y
                       : ((k & 3) == 2) ? tv.z : tv.w;
            int ti = __builtin_amdgcn_readlane(__float_as_int(comp), k >> 2);
            o = fmaf(__int_as_float(ti), Ws[k * D + lane], o);
        }
        if (do_relu) o = fmaxf(o, 0.0f);
        out[(size_t)i * D + lane] = o;
    }
}

extern "C" void kernel_launch(void* const* d_in, const int* in_sizes, int n_in,
                              void* d_out, int out_size, void* d_ws, size_t ws_size,
                              hipStream_t stream) {
    const float* x   = (const float*)d_in[0];
    const int*   src = (const int*)d_in[1];
    const int*   dst = (const int*)d_in[2];
    const float* W0  = (const float*)d_in[3];
    const float* b0  = (const float*)d_in[4];
    const float* W1  = (const float*)d_in[5];
    const float* b1  = (const float*)d_in[6];
    const float* W2  = (const float*)d_in[7];
    const float* b2  = (const float*)d_in[8];
    float* out = (float*)d_out;

    const int N = in_sizes[0] / D;   // 50000
    const int E = in_sizes[1];       // 800000

    const int scan_blocks = (N + 255) / 256;  // 196 (<= 256 required by scan_b)

    // workspace: deg | row_ptr | cursor | blocksums | col | h1 | h2 | t
    char* ws = (char*)d_ws;
    size_t off = 0;
    auto alloc = [&](size_t bytes) -> void* {
        void* p = ws + off;
        off = (off + bytes + 255) & ~(size_t)255;
        return p;
    };
    int*   deg       = (int*)  alloc((size_t)N * sizeof(int));
    int*   row_ptr   = (int*)  alloc((size_t)(N + 1) * sizeof(int));
    int*   cursor    = (int*)  alloc((size_t)N * sizeof(int));
    int*   blocksums = (int*)  alloc((size_t)scan_blocks * sizeof(int));
    int*   col       = (int*)  alloc((size_t)E * sizeof(int));
    float* h1        = (float*)alloc((size_t)N * D * sizeof(float));
    float* h2        = (float*)alloc((size_t)N * D * sizeof(float));
    float* t         = (float*)alloc((size_t)N * D * sizeof(float));

    // --- build CSR (once per call; reused by all 3 layers) ---
    hipMemsetAsync(deg, 0, (size_t)N * sizeof(int), stream);
    const int e4_blocks = (E / 4 + 255) / 256;  // 782
    const int slice_size = (N + 7) / 8;         // 6250
    count_deg_sliced_kernel<<<e4_blocks * 8, 256, 0, stream>>>(dst, deg, E, slice_size);
    scan_a_kernel<<<scan_blocks, 256, 0, stream>>>(deg, row_ptr, blocksums, N);
    scan_b_kernel<<<1, 256, 0, stream>>>(blocksums, row_ptr, scan_blocks, N);
    scan_c_kernel<<<scan_blocks, 256, 0, stream>>>(row_ptr, cursor, blocksums, N);
    fill_csr_sliced_kernel<<<e4_blocks * 8, 256, 0, stream>>>(src, dst, cursor, col, E, slice_size);

    const int gather_blocks = 2048;  // multiple of 8; 256 blocks per group
    const int mlp_blocks    = 2048;

    sage_gather_kernel<<<gather_blocks, 256, 0, stream>>>(x, row_ptr, col, t, N);
    sage_mlp_kernel<<<mlp_blocks, 256, 0, stream>>>(t, W0, b0, h1, N, 1);

    sage_gather_kernel<<<gather_blocks, 256, 0, stream>>>(h1, row_ptr, col, t, N);
    sage_mlp_kernel<<<mlp_blocks, 256, 0, stream>>>(t, W1, b1, h2, N, 1);

    sage_gather_kernel<<<gather_blocks, 256, 0, stream>>>(h2, row_ptr, col, t, N);
    sage_mlp_kernel<<<mlp_blocks, 256, 0, stream>>>(t, W2, b2, out, N, 0);
}

// Round 9
// 362.170 us; speedup vs baseline: 1.0573x; 1.0573x over previous
//
#include <hip/hip_runtime.h>

#define D 64

// --- degree histogram over dst, dst-sliced for XCD-local atomics -----------
__global__ void count_deg_sliced_kernel(const int* __restrict__ dst, int* __restrict__ deg,
                                        int nE, int slice_size) {
    const int g  = blockIdx.x & 7;    // slice id == XCD id (perf heuristic)
    const int gb = blockIdx.x >> 3;
    const int lo = g * slice_size;
    const int hi = lo + slice_size;
    int e4 = (gb * 256 + (int)threadIdx.x) * 4;
    if (e4 + 3 < nE) {
        int4 d = *(const int4*)(dst + e4);
        if (d.x >= lo && d.x < hi) atomicAdd(&deg[d.x], 1);
        if (d.y >= lo && d.y < hi) atomicAdd(&deg[d.y], 1);
        if (d.z >= lo && d.z < hi) atomicAdd(&deg[d.z], 1);
        if (d.w >= lo && d.w < hi) atomicAdd(&deg[d.w], 1);
    } else if (e4 < nE) {
        for (int e = e4; e < nE; ++e) {
            int dd = dst[e];
            if (dd >= lo && dd < hi) atomicAdd(&deg[dd], 1);
        }
    }
}

// --- hierarchical exclusive scan: A (per-block tile scan) ------------------
__global__ __launch_bounds__(256) void scan_a_kernel(const int* __restrict__ deg,
                                                     int* __restrict__ row_ptr,
                                                     int* __restrict__ blocksums, int N) {
    __shared__ int s[256];
    int t = threadIdx.x;
    int i = blockIdx.x * 256 + t;
    int v = (i < N) ? deg[i] : 0;
    s[t] = v;
    __syncthreads();
    #pragma unroll
    for (int d = 1; d < 256; d <<= 1) {
        int u = (t >= d) ? s[t - d] : 0;
        __syncthreads();
        s[t] += u;
        __syncthreads();
    }
    if (i < N) row_ptr[i] = s[t] - v;             // exclusive (block-local)
    if (t == 255) blocksums[blockIdx.x] = s[255]; // block total
}

// --- B: single-block exclusive scan of block sums (nb <= 256) --------------
__global__ __launch_bounds__(256) void scan_b_kernel(int* __restrict__ blocksums,
                                                     int* __restrict__ row_ptr,
                                                     int nb, int N) {
    __shared__ int s[256];
    int t = threadIdx.x;
    int v = (t < nb) ? blocksums[t] : 0;
    s[t] = v;
    __syncthreads();
    #pragma unroll
    for (int d = 1; d < 256; d <<= 1) {
        int u = (t >= d) ? s[t - d] : 0;
        __syncthreads();
        s[t] += u;
        __syncthreads();
    }
    if (t < nb) blocksums[t] = s[t] - v;  // exclusive block offsets
    if (t == 255) row_ptr[N] = s[255];    // total = E
}

// --- C: apply block offsets, emit final row_ptr + cursor -------------------
__global__ __launch_bounds__(256) void scan_c_kernel(int* __restrict__ row_ptr,
                                                     int* __restrict__ cursor,
                                                     const int* __restrict__ blocksums, int N) {
    int i = blockIdx.x * 256 + threadIdx.x;
    if (i < N) {
        int r = row_ptr[i] + blocksums[blockIdx.x];
        row_ptr[i] = r;
        cursor[i] = r;
    }
}

// --- bucket edges by dst: col[pos] = src, dst-sliced for XCD locality ------
__global__ __launch_bounds__(256) void fill_csr_sliced_kernel(
    const int* __restrict__ src, const int* __restrict__ dst,
    int* __restrict__ cursor, int* __restrict__ col,
    int nE, int slice_size)
{
    const int g  = blockIdx.x & 7;
    const int gb = blockIdx.x >> 3;
    const int lo = g * slice_size;
    const int hi = lo + slice_size;
    int e4 = (gb * 256 + (int)threadIdx.x) * 4;
    if (e4 + 3 < nE) {
        int4 d = *(const int4*)(dst + e4);
        bool m0 = (d.x >= lo) & (d.x < hi);
        bool m1 = (d.y >= lo) & (d.y < hi);
        bool m2 = (d.z >= lo) & (d.z < hi);
        bool m3 = (d.w >= lo) & (d.w < hi);
        if (m0 | m1 | m2 | m3) {
            int4 s = *(const int4*)(src + e4);
            if (m0) col[atomicAdd(&cursor[d.x], 1)] = s.x;
            if (m1) col[atomicAdd(&cursor[d.y], 1)] = s.y;
            if (m2) col[atomicAdd(&cursor[d.z], 1)] = s.z;
            if (m3) col[atomicAdd(&cursor[d.w], 1)] = s.w;
        }
    } else if (e4 < nE) {
        for (int e = e4; e < nE; ++e) {
            int dd = dst[e];
            if (dd >= lo && dd < hi) col[atomicAdd(&cursor[dd], 1)] = src[e];
        }
    }
}

// --- transpose row-major [N][64] -> chunked [4][N][16] ---------------------
__global__ __launch_bounds__(256) void to_chunked_kernel(const float4* __restrict__ x4,
                                                         float4* __restrict__ xc4, int N) {
    int tid = blockIdx.x * 256 + threadIdx.x;   // over N*16 float4s
    int n16 = N * 16;
    if (tid < n16) {
        int n4 = N * 4;
        int c = tid / n4;             // chunk 0..3 (uniform-ish per block)
        int r = tid - c * n4;         // i*4 + q
        int i = r >> 2, q = r & 3;
        xc4[tid] = x4[i * 16 + c * 4 + q];  // write coalesced, read 64B segs
    }
}

// --- phase 1: feature-sliced gather on CHUNKED layout ----------------------
// tc[c][i][f] = (sum_{s in N(i)} hc[c][s][f] + hc[c][i][f]) / (deg+1)
// Group g: chunk g&3, node-half g>>2. Per-XCD gather target = one chunk slab
// = N*64B = 3.2MB contiguous < 4MiB L2 -> resident; no 128B-line waste
// (R8's row-major chunk access wasted half of every line -> 104MB FETCH).
__global__ __launch_bounds__(256, 4) void sage_gather_kernel(
    const float* __restrict__ hc, const int* __restrict__ row_ptr,
    const int* __restrict__ col, float* __restrict__ tc, int N)
{
    const int g     = blockIdx.x & 7;
    const int chunk = g & 3;
    const int half  = g >> 2;
    const int gb    = blockIdx.x >> 3;
    const int lane  = threadIdx.x & 63;
    const int sub   = lane >> 4;      // edge subgroup 0..3
    const int f     = lane & 15;      // feature within chunk
    const int w     = threadIdx.x >> 6;

    const float* __restrict__ hch = hc + (size_t)chunk * N * 16;
    float* __restrict__ tch       = tc + (size_t)chunk * N * 16;

    const int Nh = (N + 1) >> 1;
    const int lo = half * Nh;
    const int hi = (lo + Nh < N) ? (lo + Nh) : N;
    const int waves_per_group = (gridDim.x >> 3) * 4;

    for (int i0 = lo + gb * 4 + w; i0 < hi; i0 += waves_per_group) {
        const int i  = __builtin_amdgcn_readfirstlane(i0);
        const int rs = __builtin_amdgcn_readfirstlane(row_ptr[i]);
        const int re = __builtin_amdgcn_readfirstlane(row_ptr[i + 1]);
        const int deg = re - rs;

        float a0 = 0.f, a1 = 0.f, a2 = 0.f, a3 = 0.f;
        for (int e0 = rs; e0 < re; e0 += 64) {
            int ee = e0 + lane;
            int idx = col[(ee < re) ? ee : (re - 1)];
            int rem = re - e0;
            int steps = (((rem < 64) ? rem : 64) + 3) >> 2;
            int tt = 0;
            for (; tt + 4 <= steps; tt += 4) {
                int base = (tt << 2) + sub;
                int s0 = __shfl(idx, base);
                int s1 = __shfl(idx, base + 4);
                int s2 = __shfl(idx, base + 8);
                int s3 = __shfl(idx, base + 12);
                a0 += hch[(size_t)s0 * 16 + f];
                a1 += hch[(size_t)s1 * 16 + f];
                a2 += hch[(size_t)s2 * 16 + f];
                a3 += hch[(size_t)s3 * 16 + f];
            }
            for (; tt < steps; ++tt) {
                int s0 = __shfl(idx, (tt << 2) + sub);
                a0 += hch[(size_t)s0 * 16 + f];
            }
        }

        float tv = (a0 + a1) + (a2 + a3);
        tv += __shfl_xor(tv, 16);
        tv += __shfl_xor(tv, 32);

        int pad = (-deg) & 3;     // clamped duplicate count of col[re-1]
        if (deg > 0 && pad) {
            int last = __builtin_amdgcn_readfirstlane(col[re - 1]);
            tv = fmaf(-(float)pad, hch[(size_t)last * 16 + f], tv);
        }
        tv = (tv + hch[(size_t)i * 16 + f]) * (1.0f / (float)(deg + 1));

        if (lane < 16) tch[(size_t)i * 16 + f] = tv;   // one full 64B line
    }
}

// --- phase 2: dense MLP out = relu?(t @ W + b), chunked t input ------------
// Lane l16=lane&15 holds chunk c=l16>>2, quad q=l16&3 of the node row.
// Feature k lives on lane ((k>>4)<<2)|((k>>2)&3), component k&3.
// out_chunked: write [4][N][16] (middle layers) else row-major (final).
__global__ __launch_bounds__(256) void sage_mlp_kernel(
    const float* __restrict__ t, const float* __restrict__ W,
    const float* __restrict__ bias, float* __restrict__ out,
    int N, int do_relu, int out_chunked)
{
    __shared__ float Ws[D * D];
    for (int i = threadIdx.x; i < D * D; i += 256) Ws[i] = W[i];
    const int lane = threadIdx.x & 63;
    const int w    = threadIdx.x >> 6;
    const float bj = bias[lane];
    __syncthreads();

    const int l16 = lane & 15;
    const size_t roff = (size_t)(l16 >> 2) * (N * 4) + (l16 & 3);  // float4 units
    const float4* __restrict__ t4 = (const float4*)t;

    // chunked store address for feature `lane`: c=lane>>4, f=lane&15
    const size_t coff = (size_t)(lane >> 4) * (N * 16) + (lane & 15);

    const int nwaves = gridDim.x * 4;
    for (int i0 = blockIdx.x * 4 + w; i0 < N; i0 += nwaves) {
        const int i = __builtin_amdgcn_readfirstlane(i0);
        float4 tv = t4[roff + (size_t)i * 4];
        float o = bj;
        #pragma unroll
        for (int k = 0; k < D; ++k) {
            float comp = ((k & 3) == 0) ? tv.x : ((k & 3) == 1) ? tv.y
                       : ((k & 3) == 2) ? tv.z : tv.w;
            int srcl = ((k >> 4) << 2) | ((k >> 2) & 3);
            int ti = __builtin_amdgcn_readlane(__float_as_int(comp), srcl);
            o = fmaf(__int_as_float(ti), Ws[k * D + lane], o);
        }
        if (do_relu) o = fmaxf(o, 0.0f);
        if (out_chunked) out[coff + (size_t)i * 16] = o;
        else             out[(size_t)i * D + lane] = o;
    }
}

extern "C" void kernel_launch(void* const* d_in, const int* in_sizes, int n_in,
                              void* d_out, int out_size, void* d_ws, size_t ws_size,
                              hipStream_t stream) {
    const float* x   = (const float*)d_in[0];
    const int*   src = (const int*)d_in[1];
    const int*   dst = (const int*)d_in[2];
    const float* W0  = (const float*)d_in[3];
    const float* b0  = (const float*)d_in[4];
    const float* W1  = (const float*)d_in[5];
    const float* b1  = (const float*)d_in[6];
    const float* W2  = (const float*)d_in[7];
    const float* b2  = (const float*)d_in[8];
    float* out = (float*)d_out;

    const int N = in_sizes[0] / D;   // 50000
    const int E = in_sizes[1];       // 800000

    const int scan_blocks = (N + 255) / 256;  // 196 (<= 256 required by scan_b)

    // workspace: deg | row_ptr | cursor | blocksums | col | A | B | tc
    // A = xc and later h2c (xc dead after first gather); B = h1c.
    char* ws = (char*)d_ws;
    size_t off = 0;
    auto alloc = [&](size_t bytes) -> void* {
        void* p = ws + off;
        off = (off + bytes + 255) & ~(size_t)255;
        return p;
    };
    int*   deg       = (int*)  alloc((size_t)N * sizeof(int));
    int*   row_ptr   = (int*)  alloc((size_t)(N + 1) * sizeof(int));
    int*   cursor    = (int*)  alloc((size_t)N * sizeof(int));
    int*   blocksums = (int*)  alloc((size_t)scan_blocks * sizeof(int));
    int*   col       = (int*)  alloc((size_t)E * sizeof(int));
    float* A         = (float*)alloc((size_t)N * D * sizeof(float));
    float* B         = (float*)alloc((size_t)N * D * sizeof(float));
    float* tc        = (float*)alloc((size_t)N * D * sizeof(float));

    // --- build CSR (once per call; reused by all 3 layers) ---
    hipMemsetAsync(deg, 0, (size_t)N * sizeof(int), stream);
    const int e4_blocks = (E / 4 + 255) / 256;  // 782
    const int slice_size = (N + 7) / 8;         // 6250
    count_deg_sliced_kernel<<<e4_blocks * 8, 256, 0, stream>>>(dst, deg, E, slice_size);
    scan_a_kernel<<<scan_blocks, 256, 0, stream>>>(deg, row_ptr, blocksums, N);
    scan_b_kernel<<<1, 256, 0, stream>>>(blocksums, row_ptr, scan_blocks, N);
    scan_c_kernel<<<scan_blocks, 256, 0, stream>>>(row_ptr, cursor, blocksums, N);
    fill_csr_sliced_kernel<<<e4_blocks * 8, 256, 0, stream>>>(src, dst, cursor, col, E, slice_size);

    // --- transpose x into chunked layout ---
    const int tr_blocks = (N * 16 + 255) / 256;  // 3125
    to_chunked_kernel<<<tr_blocks, 256, 0, stream>>>((const float4*)x, (float4*)A, N);

    const int gather_blocks = 2048;  // multiple of 8; 256 blocks per group
    const int mlp_blocks    = 2048;

    // layer 0: A(xc) -> tc -> B(h1c, chunked)
    sage_gather_kernel<<<gather_blocks, 256, 0, stream>>>(A, row_ptr, col, tc, N);
    sage_mlp_kernel<<<mlp_blocks, 256, 0, stream>>>(tc, W0, b0, B, N, 1, 1);

    // layer 1: B -> tc -> A(h2c, chunked; overwrites dead xc)
    sage_gather_kernel<<<gather_blocks, 256, 0, stream>>>(B, row_ptr, col, tc, N);
    sage_mlp_kernel<<<mlp_blocks, 256, 0, stream>>>(tc, W1, b1, A, N, 1, 1);

    // layer 2: A -> tc -> out (row-major)
    sage_gather_kernel<<<gather_blocks, 256, 0, stream>>>(A, row_ptr, col, tc, N);
    sage_mlp_kernel<<<mlp_blocks, 256, 0, stream>>>(tc, W2, b2, out, N, 0, 0);
}